// Round 3
// baseline (188.611 us; speedup 1.0000x reference)
//
#include <hip/hip_runtime.h>
#include <hip/hip_bf16.h>

constexpr int Bn   = 32;
constexpr int CIN  = 128;
constexpr int Hh   = 56;
constexpr int Ww   = 56;
constexpr int HW   = Hh * Ww;      // 3136
constexpr int COUT = 128;
constexpr int En   = 8;

typedef __attribute__((ext_vector_type(8))) short bf16x8;   // 8 bf16 (4 VGPRs)
typedef __attribute__((ext_vector_type(4))) float f32x4;

struct GateInfo { int e0, e1; float w0, w1; };

// ---- workspace layout (bytes) ----
constexpr size_t XB_OFF  = 0;                               // bf16 NHWC x
constexpr size_t XB_SZ   = (size_t)Bn * HW * CIN * 2;       // 25,690,112
constexpr size_t WW_OFF  = XB_OFF + XB_SZ;                  // bf16 combined W [b][tap][cout][cin]
constexpr size_t WW_SZ   = (size_t)Bn * 9 * COUT * CIN * 2; // 9,437,184
constexpr size_t HS_OFF  = WW_OFF + WW_SZ;                  // f32 per-(b,h,c) row sums
constexpr size_t HS_SZ   = (size_t)Bn * Hh * CIN * 4;       // 917,504
constexpr size_t GAP_OFF = HS_OFF + HS_SZ;                  // f32 gap [b][c]
constexpr size_t GAP_SZ  = (size_t)Bn * CIN * 4;
constexpr size_t GI_OFF  = GAP_OFF + GAP_SZ;                // GateInfo[32]

// ---------------- 1: NCHW f32 -> NHWC bf16, fused per-row sums ----------------
// grid = Bn*Hh blocks (b,h), 256 threads
__global__ __launch_bounds__(256) void convert_kernel(const float* __restrict__ x,
        __hip_bfloat16* __restrict__ xbf, float* __restrict__ hsum) {
    __shared__ float lt[CIN * 57];   // [c][w], stride 57 (odd) for transpose reads
    int gid = blockIdx.x;
    int b = gid / Hh, h = gid % Hh;
    const float* xp = x + (size_t)b * CIN * HW + h * Ww;
    for (int u = threadIdx.x; u < CIN * Ww; u += 256) {
        int c = u / Ww, w = u % Ww;
        lt[c * 57 + w] = xp[(size_t)c * HW + w];
    }
    __syncthreads();
    __hip_bfloat16* xo = xbf + ((size_t)b * HW + h * Ww) * CIN;
    // packed 16B stores: unit (w, cg) = 8 consecutive cins
    for (int u = threadIdx.x; u < 16 * Ww; u += 256) {
        int w = u >> 4, cg = u & 15;
        bf16x8 pk;
        #pragma unroll
        for (int j = 0; j < 8; j++) {
            __hip_bfloat16 t = __float2bfloat16(lt[(cg * 8 + j) * 57 + w]);
            pk[j] = *reinterpret_cast<short*>(&t);
        }
        *(bf16x8*)(xo + (size_t)w * CIN + cg * 8) = pk;
    }
    if (threadIdx.x < CIN) {
        int c = threadIdx.x;
        float s = 0.f;
        #pragma unroll 8
        for (int w = 0; w < Ww; w++) s += lt[c * 57 + w];
        hsum[((size_t)b * Hh + h) * CIN + c] = s;
    }
}

// ---------------- 2: finish GAP ----------------
__global__ void gap2_kernel(const float* __restrict__ hsum, float* __restrict__ gap) {
    int t = blockIdx.x * 256 + threadIdx.x;        // 4096 = Bn*CIN
    int b = t >> 7, c = t & 127;
    float s = 0.f;
    for (int h = 0; h < Hh; h++) s += hsum[((size_t)b * Hh + h) * CIN + c];
    gap[t] = s * (1.f / (float)HW);
}

// ---------------- 3: gate (logits -> top2 -> softmax) ----------------
__global__ void gate_kernel(const float* __restrict__ gap,
                            const float* __restrict__ gate_w,
                            const float* __restrict__ gate_b,
                            float* __restrict__ wout,
                            GateInfo* __restrict__ info) {
    __shared__ float logits[Bn][En];
    __shared__ GateInfo gi[Bn];
    int tid = threadIdx.x;
    int b = tid >> 3, e = tid & 7;
    float s = gate_b[e];
    const float* g = gap + b * CIN;
    const float* w = gate_w + e * CIN;
    #pragma unroll 8
    for (int c = 0; c < CIN; c++) s += g[c] * w[c];
    logits[b][e] = s;
    __syncthreads();
    if (tid < Bn) {
        float v[En];
        #pragma unroll
        for (int k = 0; k < En; k++) v[k] = logits[tid][k];
        int i0 = 0; float m0 = v[0];
        #pragma unroll
        for (int k = 1; k < En; k++) if (v[k] > m0) { m0 = v[k]; i0 = k; }
        int i1 = -1; float m1 = -1e30f;
        #pragma unroll
        for (int k = 0; k < En; k++) if (k != i0 && v[k] > m1) { m1 = v[k]; i1 = k; }
        float ex = expf(m1 - m0);
        float den = 1.f + ex;
        GateInfo t; t.e0 = i0; t.e1 = i1; t.w0 = 1.f / den; t.w1 = ex / den;
        gi[tid] = t;
        info[tid] = t;
    }
    __syncthreads();
    {
        int bb = tid >> 3, ee = tid & 7;
        GateInfo t = gi[bb];
        wout[tid] = (ee == t.e0) ? t.w0 : (ee == t.e1) ? t.w1 : 0.f;
    }
}

// ---------------- 4: combined weights -> bf16 [b][tap][cout][cin] ----------------
// grid = Bn*8 blocks (b, cout-group of 16), 256 threads
__global__ __launch_bounds__(256) void wcomb_kernel(const float* __restrict__ cw,
        const GateInfo* __restrict__ info, __hip_bfloat16* __restrict__ wws) {
    __shared__ __hip_bfloat16 wl[16 * 1152];       // [co][cin][tap]
    int b = blockIdx.x >> 3, cg = blockIdx.x & 7;
    GateInfo gi = info[b];
    const float* p0 = cw + (size_t)gi.e0 * COUT * CIN * 9 + (size_t)cg * 16 * 1152;
    const float* p1 = cw + (size_t)gi.e1 * COUT * CIN * 9 + (size_t)cg * 16 * 1152;
    for (int u = threadIdx.x; u < 16 * 1152; u += 256)
        wl[u] = __float2bfloat16(gi.w0 * p0[u] + gi.w1 * p1[u]);
    __syncthreads();
    __hip_bfloat16* wo = wws + (size_t)b * 9 * COUT * CIN + (size_t)cg * 16 * CIN;
    for (int u = threadIdx.x; u < 16 * 1152; u += 256) {
        int t = u / 2048, rem = u & 2047;
        int co = rem >> 7, cin = rem & 127;
        wo[(size_t)t * COUT * CIN + co * CIN + cin] = wl[co * 1152 + cin * 9 + t];
    }
}

// ---------------- 5: implicit-GEMM conv via MFMA ----------------
// Block: (b, cout half of 64, row block of 8) -> 448 blocks, 256 thr = 4 waves.
// Waves: 1M x 4N. Wave tile: M=64 (4 Mtiles) x N=112 (7 Ntiles).
// XCD swizzle: xcd = bid&7 owns 4 consecutive samples (1.1 MB/sample fits 4MB L2).
// LDS X chunk: 32 cins x 10 rows x 58 cols as 4 k-planes of 580 16B units,
// plane stride 581 units; staging maps consecutive lanes -> consecutive units
// (conflict-free ds_write_b128).
constexpr int USz = 581;

__global__ __launch_bounds__(256, 3) void conv_mfma(
        const __hip_bfloat16* __restrict__ xbf,
        const __hip_bfloat16* __restrict__ wws,
        float* __restrict__ out) {
    __shared__ char xs[4 * USz * 16];              // 37,184 B

    int bid = blockIdx.x;
    int xcd = bid & 7, k = bid >> 3;               // round-robin dispatch -> XCD = bid%8
    int b   = xcd * 4 + k / 14;
    int rem = k % 14;
    int cb  = rem / 7, rb = rem % 7;
    int row0 = rb * 8, cout0 = cb * 64;
    int tid = threadIdx.x, wave = tid >> 6, lane = tid & 63;
    int wn = wave;                                 // 4 N-quarters
    int l15 = lane & 15, lk = lane >> 4;

    // per-lane LDS byte base for each N-tile (B fragment); tap adds (dr*58+dc)*16
    int bbase[7];
    #pragma unroll
    for (int i = 0; i < 7; i++) {
        int p = wn * 112 + i * 16 + l15;           // pixel within the 448-span
        int r = p / 56, c = p % 56;
        bbase[i] = (lk * USz + (r * 58 + c)) * 16;
    }

    const __hip_bfloat16* wwb = wws + (size_t)b * 9 * COUT * CIN;
    const __hip_bfloat16* ap  = wwb + (size_t)(cout0 + l15) * CIN + lk * 8;

    f32x4 acc[4][7];
    #pragma unroll
    for (int mt = 0; mt < 4; mt++)
        #pragma unroll
        for (int i = 0; i < 7; i++) acc[mt][i] = (f32x4){0.f, 0.f, 0.f, 0.f};

    for (int c0 = 0; c0 < CIN; c0 += 32) {
        __syncthreads();
        // stage 32 cins x 10 rows x 58 cols: 2320 16B units, lanes sequential
        const __hip_bfloat16* xbb = xbf + (size_t)b * HW * CIN + c0;
        for (int u = tid; u < 2320; u += 256) {
            int ul = u / 580, rc = u % 580;
            int lr = rc / 58, lc = rc % 58;
            int grow = row0 - 1 + lr, gw = lc - 1;
            int4 v = {0, 0, 0, 0};
            if ((unsigned)grow < 56u && (unsigned)gw < 56u)
                v = *(const int4*)(xbb + ((size_t)grow * 56 + gw) * CIN + ul * 8);
            *(int4*)(xs + (ul * USz + rc) * 16) = v;
        }
        __syncthreads();

        #pragma unroll
        for (int t = 0; t < 9; t++) {
            const int dr = t / 3, dc = t % 3;
            const __hip_bfloat16* at = ap + (size_t)t * COUT * CIN + c0;
            bf16x8 a[4];
            #pragma unroll
            for (int mt = 0; mt < 4; mt++)
                a[mt] = *(const bf16x8*)(at + mt * 16 * CIN);
            const int toff = (dr * 58 + dc) * 16;
            #pragma unroll
            for (int i = 0; i < 7; i++) {
                bf16x8 bv = *(const bf16x8*)(xs + bbase[i] + toff);
                #pragma unroll
                for (int mt = 0; mt < 4; mt++)
                    acc[mt][i] = __builtin_amdgcn_mfma_f32_16x16x32_bf16(a[mt], bv, acc[mt][i], 0, 0, 0);
            }
        }
    }

    // epilogue: C/D layout col=lane&15 (pixel), row=(lane>>4)*4+j (cout)
    float* outb = out + (size_t)b * COUT * HW + row0 * 56;
    #pragma unroll
    for (int mt = 0; mt < 4; mt++) {
        int cbase = cout0 + mt * 16 + lk * 4;
        #pragma unroll
        for (int i = 0; i < 7; i++) {
            int pp = wn * 112 + i * 16 + l15;
            #pragma unroll
            for (int j = 0; j < 4; j++)
                outb[(size_t)(cbase + j) * HW + pp] = acc[mt][i][j];
        }
    }
}

// ---------------- launch ----------------
extern "C" void kernel_launch(void* const* d_in, const int* in_sizes, int n_in,
                              void* d_out, int out_size, void* d_ws, size_t ws_size,
                              hipStream_t stream) {
    const float* x  = (const float*)d_in[0];
    const float* cw = (const float*)d_in[1];
    const float* gw = (const float*)d_in[2];
    const float* gb = (const float*)d_in[3];

    float* out = (float*)d_out;
    char* ws = (char*)d_ws;
    __hip_bfloat16* xbf  = (__hip_bfloat16*)(ws + XB_OFF);
    __hip_bfloat16* wws  = (__hip_bfloat16*)(ws + WW_OFF);
    float* hsum          = (float*)(ws + HS_OFF);
    float* gap           = (float*)(ws + GAP_OFF);
    GateInfo* info       = (GateInfo*)(ws + GI_OFF);
    float* wout = out + (size_t)Bn * COUT * HW;

    convert_kernel<<<Bn * Hh, 256, 0, stream>>>(x, xbf, hsum);
    gap2_kernel   <<<16,      256, 0, stream>>>(hsum, gap);
    gate_kernel   <<<1,       256, 0, stream>>>(gap, gw, gb, wout, info);
    wcomb_kernel  <<<Bn * 8,  256, 0, stream>>>(cw, info, wws);
    conv_mfma     <<<448, 256, 0, stream>>>(xbf, wws, out);
}

// Round 4
// 178.385 us; speedup vs baseline: 1.0573x; 1.0573x over previous
//
#include <hip/hip_runtime.h>
#include <hip/hip_bf16.h>

constexpr int Bn   = 32;
constexpr int CIN  = 128;
constexpr int Hh   = 56;
constexpr int Ww   = 56;
constexpr int HW   = Hh * Ww;      // 3136
constexpr int COUT = 128;
constexpr int En   = 8;

typedef __attribute__((ext_vector_type(8))) short bf16x8;   // 8 bf16 (4 VGPRs)
typedef __attribute__((ext_vector_type(4))) float f32x4;

struct GateInfo { int e0, e1; float w0, w1; };

// ---- xpad: [b][g=cin/32][row 0..57][col 0..57][32 cin] bf16, zero borders ----
constexpr size_t ROWB = 58 * 32 * 2;        // 3712 B per padded row slab-line
constexpr size_t PGB  = 58 * ROWB;          // 215,296 B per (b,g) plane

// ---- workspace layout (bytes) ----
constexpr size_t XP_OFF  = 0;
constexpr size_t XP_SZ   = (size_t)Bn * 4 * PGB;            // 27,557,888
constexpr size_t WW_OFF  = XP_OFF + XP_SZ;                  // bf16 combined W [b][tap][cout][cin]
constexpr size_t WW_SZ   = (size_t)Bn * 9 * COUT * CIN * 2; // 9,437,184
constexpr size_t HS_OFF  = WW_OFF + WW_SZ;                  // f32 per-(b,h,c) row sums
constexpr size_t HS_SZ   = (size_t)Bn * Hh * CIN * 4;
constexpr size_t GAP_OFF = HS_OFF + HS_SZ;
constexpr size_t GAP_SZ  = (size_t)Bn * CIN * 4;
constexpr size_t GI_OFF  = GAP_OFF + GAP_SZ;

__device__ inline void gload_lds16(const void* g, void* l) {
    __builtin_amdgcn_global_load_lds(
        (const __attribute__((address_space(1))) unsigned int*)g,
        (__attribute__((address_space(3))) unsigned int*)l, 16, 0, 0);
}

// ---------------- 0: zero the xpad borders (re-run every launch; ws is poisoned) ----------------
// grid = Bn*4 blocks, one per (b,g) plane
__global__ __launch_bounds__(256) void zero_kernel(char* __restrict__ xpad) {
    char* pl = xpad + (size_t)blockIdx.x * PGB;
    for (int u = threadIdx.x; u < 912; u += 256) {
        size_t off;
        if (u < 232)      off = (size_t)u * 16;                        // row 0
        else if (u < 464) off = 57 * ROWB + (size_t)(u - 232) * 16;    // row 57
        else {
            int v = u - 464;                                           // cols 0/57, rows 1..56
            int r = v / 8 + 1, s = (v & 7) >> 2, a = v & 3;
            off = (size_t)r * ROWB + (s ? 57 : 0) * 64 + a * 16;
        }
        *(int4*)(pl + off) = (int4){0, 0, 0, 0};
    }
}

// ---------------- 1: NCHW f32 -> xpad bf16, fused per-row sums ----------------
// grid = Bn*Hh blocks (b,h), 256 threads
__global__ __launch_bounds__(256) void convert_kernel(const float* __restrict__ x,
        char* __restrict__ xpad, float* __restrict__ hsum) {
    __shared__ float lt[CIN * 57];   // [c][w], stride 57 (odd) for transpose reads
    int gid = blockIdx.x;
    int b = gid / Hh, h = gid % Hh;
    const float* xp = x + (size_t)b * CIN * HW + h * Ww;
    for (int u = threadIdx.x; u < CIN * Ww; u += 256) {
        int c = u / Ww, w = u % Ww;
        lt[c * 57 + w] = xp[(size_t)c * HW + w];
    }
    __syncthreads();
    char* dst = xpad + (size_t)b * 4 * PGB + (size_t)(h + 1) * ROWB;
    // 896 16B units: u = g*224 + w*4 + a  (64 consecutive lanes -> 1KB contiguous per g)
    for (int u = threadIdx.x; u < 896; u += 256) {
        int g = u / 224, r = u % 224, w = r >> 2, a = r & 3;
        bf16x8 pk;
        #pragma unroll
        for (int j = 0; j < 8; j++) {
            __hip_bfloat16 t = __float2bfloat16(lt[(g * 32 + a * 8 + j) * 57 + w]);
            pk[j] = *reinterpret_cast<short*>(&t);
        }
        *(bf16x8*)(dst + (size_t)g * PGB + (size_t)(w + 1) * 64 + a * 16) = pk;
    }
    if (threadIdx.x < CIN) {
        int c = threadIdx.x;
        float s = 0.f;
        #pragma unroll 8
        for (int w = 0; w < Ww; w++) s += lt[c * 57 + w];
        hsum[((size_t)b * Hh + h) * CIN + c] = s;
    }
}

// ---------------- 2: finish GAP ----------------
__global__ void gap2_kernel(const float* __restrict__ hsum, float* __restrict__ gap) {
    int t = blockIdx.x * 256 + threadIdx.x;        // 4096 = Bn*CIN
    int b = t >> 7, c = t & 127;
    float s = 0.f;
    for (int h = 0; h < Hh; h++) s += hsum[((size_t)b * Hh + h) * CIN + c];
    gap[t] = s * (1.f / (float)HW);
}

// ---------------- 3: gate (logits -> top2 -> softmax) ----------------
__global__ void gate_kernel(const float* __restrict__ gap,
                            const float* __restrict__ gate_w,
                            const float* __restrict__ gate_b,
                            float* __restrict__ wout,
                            GateInfo* __restrict__ info) {
    __shared__ float logits[Bn][En];
    __shared__ GateInfo gi[Bn];
    int tid = threadIdx.x;
    int b = tid >> 3, e = tid & 7;
    float s = gate_b[e];
    const float* g = gap + b * CIN;
    const float* w = gate_w + e * CIN;
    #pragma unroll 8
    for (int c = 0; c < CIN; c++) s += g[c] * w[c];
    logits[b][e] = s;
    __syncthreads();
    if (tid < Bn) {
        float v[En];
        #pragma unroll
        for (int k = 0; k < En; k++) v[k] = logits[tid][k];
        int i0 = 0; float m0 = v[0];
        #pragma unroll
        for (int k = 1; k < En; k++) if (v[k] > m0) { m0 = v[k]; i0 = k; }
        int i1 = -1; float m1 = -1e30f;
        #pragma unroll
        for (int k = 0; k < En; k++) if (k != i0 && v[k] > m1) { m1 = v[k]; i1 = k; }
        float ex = expf(m1 - m0);
        float den = 1.f + ex;
        GateInfo t; t.e0 = i0; t.e1 = i1; t.w0 = 1.f / den; t.w1 = ex / den;
        gi[tid] = t;
        info[tid] = t;
    }
    __syncthreads();
    {
        int bb = tid >> 3, ee = tid & 7;
        GateInfo t = gi[bb];
        wout[tid] = (ee == t.e0) ? t.w0 : (ee == t.e1) ? t.w1 : 0.f;
    }
}

// ---------------- 4: combined weights -> bf16 [b][tap][cout][cin] ----------------
// grid = Bn*8 blocks (b, cout-group of 16), 256 threads
__global__ __launch_bounds__(256) void wcomb_kernel(const float* __restrict__ cw,
        const GateInfo* __restrict__ info, __hip_bfloat16* __restrict__ wws) {
    __shared__ __hip_bfloat16 wl[16 * 1152];       // [co][cin][tap]
    int b = blockIdx.x >> 3, cg = blockIdx.x & 7;
    GateInfo gi = info[b];
    const float* p0 = cw + (size_t)gi.e0 * COUT * CIN * 9 + (size_t)cg * 16 * 1152;
    const float* p1 = cw + (size_t)gi.e1 * COUT * CIN * 9 + (size_t)cg * 16 * 1152;
    for (int u = threadIdx.x; u < 16 * 1152; u += 256)
        wl[u] = __float2bfloat16(gi.w0 * p0[u] + gi.w1 * p1[u]);
    __syncthreads();
    __hip_bfloat16* wo = wws + (size_t)b * 9 * COUT * CIN + (size_t)cg * 16 * CIN;
    // vectorized scatter: u = t*256 + co*16 + a  -> 16B store of 8 cins
    for (int u = threadIdx.x; u < 2304; u += 256) {
        int t = u >> 8, rem = u & 255, co = rem >> 4, a = rem & 15;
        bf16x8 pk;
        #pragma unroll
        for (int j = 0; j < 8; j++)
            pk[j] = *reinterpret_cast<short*>(&wl[co * 1152 + (a * 8 + j) * 9 + t]);
        *(bf16x8*)(wo + (size_t)t * COUT * CIN + co * CIN + a * 8) = pk;
    }
}

// ---------------- 5: implicit-GEMM conv via MFMA, 2-phase async pipeline ----------------
// 896 blocks = 8 XCD x (4 samples x 2 cout-halves x 14 row-blocks of 4).
// 256 thr = 4 waves, 2M x 2N; wave tile M=32 (2 Mtiles) x N=112 (7 Ntiles).
// LDS: double-buffered 22.5KB slab = 6 padded rows x 58 cols x 32 cins,
// staged by global_load_lds(16B) from contiguous xpad; next chunk issued
// before current chunk's compute (loads fly under the MFMAs).
__global__ __launch_bounds__(256, 3) void conv_mfma(
        const char* __restrict__ xpad,
        const __hip_bfloat16* __restrict__ wws,
        float* __restrict__ out) {
    __shared__ char xs[2][22528];

    int bid = blockIdx.x;
    int xcd = bid & 7, k = bid >> 3;               // XCD owns 4 consecutive samples
    int b   = xcd * 4 + k / 28;
    int r2  = k % 28;
    int cb  = r2 / 14, rb = r2 % 14;
    int row0 = rb * 4, cout0 = cb * 64;
    int tid = threadIdx.x, wave = tid >> 6, lane = tid & 63;
    int wm = wave >> 1, wn = wave & 1;
    int l15 = lane & 15, lk = lane >> 4;

    const char* src = xpad + (size_t)b * 4 * PGB + (size_t)row0 * ROWB;

    // per-lane LDS byte base per N-tile; tap adds dr*ROWB + dc*64
    int bbase[7];
    #pragma unroll
    for (int i = 0; i < 7; i++) {
        int p = wn * 112 + i * 16 + l15;
        bbase[i] = (p / 56) * (int)ROWB + (p % 56) * 64 + lk * 16;
    }

    const __hip_bfloat16* ap = wws + (size_t)b * 9 * COUT * CIN
                             + (size_t)(cout0 + wm * 32 + l15) * CIN + lk * 8;

    f32x4 acc[2][7];
    #pragma unroll
    for (int mt = 0; mt < 2; mt++)
        #pragma unroll
        for (int i = 0; i < 7; i++) acc[mt][i] = (f32x4){0.f, 0.f, 0.f, 0.f};

    // prologue: stage chunk 0 (22 x 1KB wave-loads; waves 0,1 take 6, waves 2,3 take 5)
    #pragma unroll
    for (int i2 = 0; i2 < 6; i2++) {
        int idx = i2 * 4 + wave;
        if (idx < 22)
            gload_lds16(src + idx * 1024 + lane * 16, &xs[0][idx * 1024]);
    }

    for (int g = 0; g < 4; ++g) {
        __syncthreads();                           // drains vmcnt -> xs[g&1] ready
        if (g < 3) {                               // issue next chunk now; flies under MFMA
            const char* s2 = src + (size_t)(g + 1) * PGB;
            #pragma unroll
            for (int i2 = 0; i2 < 6; i2++) {
                int idx = i2 * 4 + wave;
                if (idx < 22)
                    gload_lds16(s2 + idx * 1024 + lane * 16, &xs[(g + 1) & 1][idx * 1024]);
            }
        }
        const char* xb = xs[g & 1];
        const __hip_bfloat16* at0 = ap + g * 32;   // cin chunk offset
        #pragma unroll
        for (int t = 0; t < 9; t++) {
            const int dr = t / 3, dc = t % 3;
            const __hip_bfloat16* at = at0 + (size_t)t * COUT * CIN;
            bf16x8 a0 = *(const bf16x8*)(at);
            bf16x8 a1 = *(const bf16x8*)(at + 16 * CIN);
            const int toff = dr * (int)ROWB + dc * 64;
            #pragma unroll
            for (int i = 0; i < 7; i++) {
                bf16x8 bv = *(const bf16x8*)(xb + bbase[i] + toff);
                acc[0][i] = __builtin_amdgcn_mfma_f32_16x16x32_bf16(a0, bv, acc[0][i], 0, 0, 0);
                acc[1][i] = __builtin_amdgcn_mfma_f32_16x16x32_bf16(a1, bv, acc[1][i], 0, 0, 0);
            }
        }
    }

    // epilogue: C/D layout col=lane&15 (pixel), row=(lane>>4)*4+j (cout)
    float* outb = out + (size_t)b * COUT * HW + row0 * 56;
    #pragma unroll
    for (int mt = 0; mt < 2; mt++) {
        int cbase = cout0 + wm * 32 + mt * 16 + lk * 4;
        #pragma unroll
        for (int i = 0; i < 7; i++) {
            int pp = wn * 112 + i * 16 + l15;
            #pragma unroll
            for (int j = 0; j < 4; j++)
                outb[(size_t)(cbase + j) * HW + pp] = acc[mt][i][j];
        }
    }
}

// ---------------- launch ----------------
extern "C" void kernel_launch(void* const* d_in, const int* in_sizes, int n_in,
                              void* d_out, int out_size, void* d_ws, size_t ws_size,
                              hipStream_t stream) {
    const float* x  = (const float*)d_in[0];
    const float* cw = (const float*)d_in[1];
    const float* gw = (const float*)d_in[2];
    const float* gb = (const float*)d_in[3];

    float* out = (float*)d_out;
    char* ws = (char*)d_ws;
    char* xpad           = ws + XP_OFF;
    __hip_bfloat16* wws  = (__hip_bfloat16*)(ws + WW_OFF);
    float* hsum          = (float*)(ws + HS_OFF);
    float* gap           = (float*)(ws + GAP_OFF);
    GateInfo* info       = (GateInfo*)(ws + GI_OFF);
    float* wout = out + (size_t)Bn * COUT * HW;

    zero_kernel   <<<Bn * 4,  256, 0, stream>>>(xpad);
    convert_kernel<<<Bn * Hh, 256, 0, stream>>>(x, xpad, hsum);
    gap2_kernel   <<<16,      256, 0, stream>>>(hsum, gap);
    gate_kernel   <<<1,       256, 0, stream>>>(gap, gw, gb, wout, info);
    wcomb_kernel  <<<Bn * 8,  256, 0, stream>>>(cw, info, wws);
    conv_mfma     <<<896,     256, 0, stream>>>(xpad, wws, out);
}

// Round 5
// 170.707 us; speedup vs baseline: 1.1049x; 1.0450x over previous
//
#include <hip/hip_runtime.h>
#include <hip/hip_bf16.h>

constexpr int Bn   = 32;
constexpr int CIN  = 128;
constexpr int Hh   = 56;
constexpr int Ww   = 56;
constexpr int HW   = Hh * Ww;      // 3136
constexpr int COUT = 128;
constexpr int En   = 8;

typedef __attribute__((ext_vector_type(8))) short bf16x8;   // 8 bf16 (4 VGPRs)
typedef __attribute__((ext_vector_type(4))) float f32x4;

struct GateInfo { int e0, e1; float w0, w1; };

// ---- xpad: [b][g=cin/32][row 0..57][col 0..57][4 quarters x 8 cin] bf16 ----
// quarter swizzle: physical quarter pq holds logical quarter (pq - (col>>1)) & 3
constexpr size_t ROWB = 58 * 64;            // 3712 B per padded row line
constexpr size_t PGB  = 58 * ROWB;          // 215,296 B per (b,g) plane
constexpr int TAPSTR  = COUT * CIN;         // 16384 elems per tap in wws

// ---- workspace layout (bytes) ----
constexpr size_t XP_OFF  = 0;
constexpr size_t XP_SZ   = (size_t)Bn * 4 * PGB;            // 27,557,888
constexpr size_t WW_OFF  = XP_OFF + XP_SZ;                  // bf16 combined W [b][tap][cout][cin]
constexpr size_t WW_SZ   = (size_t)Bn * 9 * COUT * CIN * 2; // 9,437,184
constexpr size_t HS_OFF  = WW_OFF + WW_SZ;                  // f32 per-(b,h,c) row sums
constexpr size_t HS_SZ   = (size_t)Bn * Hh * CIN * 4;
constexpr size_t GAP_OFF = HS_OFF + HS_SZ;
constexpr size_t GAP_SZ  = (size_t)Bn * CIN * 4;
constexpr size_t GI_OFF  = GAP_OFF + GAP_SZ;

__device__ inline void gload_lds16(const void* g, void* l) {
    __builtin_amdgcn_global_load_lds(
        (const __attribute__((address_space(1))) unsigned int*)g,
        (__attribute__((address_space(3))) unsigned int*)l, 16, 0, 0);
}

// ---------------- 1: NCHW f32 -> xpad bf16 (swizzled quarters), borders zeroed, row sums ----------------
// grid = Bn*Hh blocks (b,h), 256 threads
__global__ __launch_bounds__(256) void convert_kernel(const float* __restrict__ x,
        char* __restrict__ xpad, float* __restrict__ hsum) {
    __shared__ float lt[CIN * 57];   // [c][w], stride 57 (odd) for transpose reads
    int gid = blockIdx.x;
    int b = gid / Hh, h = gid % Hh;
    const float* xp = x + (size_t)b * CIN * HW + h * Ww;
    for (int u = threadIdx.x; u < CIN * Ww; u += 256) {
        int c = u / Ww, w = u % Ww;
        lt[c * 57 + w] = xp[(size_t)c * HW + w];
    }
    __syncthreads();
    char* dst = xpad + (size_t)b * 4 * PGB + (size_t)(h + 1) * ROWB;
    // 896 16B units: u = g*224 + w*4 + a; physical slot = (a + ((w+1)>>1)) & 3
    for (int u = threadIdx.x; u < 896; u += 256) {
        int g = u / 224, r = u % 224, w = r >> 2, a = r & 3;
        bf16x8 pk;
        #pragma unroll
        for (int j = 0; j < 8; j++) {
            __hip_bfloat16 t = __float2bfloat16(lt[(g * 32 + a * 8 + j) * 57 + w]);
            pk[j] = *reinterpret_cast<short*>(&t);
        }
        int pq = (a + ((w + 1) >> 1)) & 3;
        *(bf16x8*)(dst + (size_t)g * PGB + (size_t)(w + 1) * 64 + pq * 16) = pk;
    }
    // zero col borders (cols 0 and 57) for this row, all 4 g-planes
    if (threadIdx.x < 32) {
        int t = threadIdx.x, g = t >> 3, side = (t >> 2) & 1, q = t & 3;
        *(int4*)(xpad + (size_t)b * 4 * PGB + (size_t)g * PGB + (size_t)(h + 1) * ROWB
                 + (side ? 57 : 0) * 64 + q * 16) = (int4){0, 0, 0, 0};
    }
    // first/last h-blocks zero full rows 0 / 57
    if (h == 0 || h == 55) {
        int row = (h == 0) ? 0 : 57;
        char* base = xpad + (size_t)b * 4 * PGB + (size_t)row * ROWB;
        for (int u = threadIdx.x; u < 928; u += 256) {
            int g = u / 232, r = u % 232;
            *(int4*)(base + (size_t)g * PGB + (size_t)r * 16) = (int4){0, 0, 0, 0};
        }
    }
    if (threadIdx.x < CIN) {
        int c = threadIdx.x;
        float s = 0.f;
        #pragma unroll 8
        for (int w = 0; w < Ww; w++) s += lt[c * 57 + w];
        hsum[((size_t)b * Hh + h) * CIN + c] = s;
    }
}

// ---------------- 2: finish GAP ----------------
__global__ void gap2_kernel(const float* __restrict__ hsum, float* __restrict__ gap) {
    int t = blockIdx.x * 256 + threadIdx.x;        // 4096 = Bn*CIN
    int b = t >> 7, c = t & 127;
    float s = 0.f;
    for (int h = 0; h < Hh; h++) s += hsum[((size_t)b * Hh + h) * CIN + c];
    gap[t] = s * (1.f / (float)HW);
}

// ---------------- 3: gate (logits -> top2 -> softmax) ----------------
__global__ void gate_kernel(const float* __restrict__ gap,
                            const float* __restrict__ gate_w,
                            const float* __restrict__ gate_b,
                            float* __restrict__ wout,
                            GateInfo* __restrict__ info) {
    __shared__ float logits[Bn][En];
    __shared__ GateInfo gi[Bn];
    int tid = threadIdx.x;
    int b = tid >> 3, e = tid & 7;
    float s = gate_b[e];
    const float* g = gap + b * CIN;
    const float* w = gate_w + e * CIN;
    #pragma unroll 8
    for (int c = 0; c < CIN; c++) s += g[c] * w[c];
    logits[b][e] = s;
    __syncthreads();
    if (tid < Bn) {
        float v[En];
        #pragma unroll
        for (int k = 0; k < En; k++) v[k] = logits[tid][k];
        int i0 = 0; float m0 = v[0];
        #pragma unroll
        for (int k = 1; k < En; k++) if (v[k] > m0) { m0 = v[k]; i0 = k; }
        int i1 = -1; float m1 = -1e30f;
        #pragma unroll
        for (int k = 0; k < En; k++) if (k != i0 && v[k] > m1) { m1 = v[k]; i1 = k; }
        float ex = expf(m1 - m0);
        float den = 1.f + ex;
        GateInfo t; t.e0 = i0; t.e1 = i1; t.w0 = 1.f / den; t.w1 = ex / den;
        gi[tid] = t;
        info[tid] = t;
    }
    __syncthreads();
    {
        int bb = tid >> 3, ee = tid & 7;
        GateInfo t = gi[bb];
        wout[tid] = (ee == t.e0) ? t.w0 : (ee == t.e1) ? t.w1 : 0.f;
    }
}

// ---------------- 4: combined weights -> bf16 [b][tap][cout][cin] ----------------
// grid = Bn*8 blocks (b, cout-group of 16), 256 threads
__global__ __launch_bounds__(256) void wcomb_kernel(const float* __restrict__ cw,
        const GateInfo* __restrict__ info, __hip_bfloat16* __restrict__ wws) {
    __shared__ __hip_bfloat16 wl[16 * 1152];       // [co][cin][tap]
    int b = blockIdx.x >> 3, cg = blockIdx.x & 7;
    GateInfo gi = info[b];
    const float* p0 = cw + (size_t)gi.e0 * COUT * CIN * 9 + (size_t)cg * 16 * 1152;
    const float* p1 = cw + (size_t)gi.e1 * COUT * CIN * 9 + (size_t)cg * 16 * 1152;
    for (int u = threadIdx.x; u < 16 * 1152; u += 256)
        wl[u] = __float2bfloat16(gi.w0 * p0[u] + gi.w1 * p1[u]);
    __syncthreads();
    __hip_bfloat16* wo = wws + (size_t)b * 9 * COUT * CIN + (size_t)cg * 16 * CIN;
    // vectorized scatter: u = t*256 + co*16 + a  -> 16B store of 8 cins
    for (int u = threadIdx.x; u < 2304; u += 256) {
        int t = u >> 8, rem = u & 255, co = rem >> 4, a = rem & 15;
        bf16x8 pk;
        #pragma unroll
        for (int j = 0; j < 8; j++)
            pk[j] = *reinterpret_cast<short*>(&wl[co * 1152 + (a * 8 + j) * 9 + t]);
        *(bf16x8*)(wo + (size_t)t * COUT * CIN + co * CIN + a * 8) = pk;
    }
}

// ---------------- 5: implicit-GEMM conv via MFMA ----------------
// 448 blocks = 8 XCD x (4 samples x 14 row-blocks of 4).  256 thr = 4 waves:
// wave = (cout-half cb, N-half wn).  Wave tile: M=64 (4 Mtiles, Mrep=4 per
// B-read -> LDS demand 50% of capacity) x N=112 (7 Ntiles).
// LDS: double-buffered 22528B slab = 6 padded rows x 58 cols x 64B units,
// quarter-swizzled; staged linearly by global_load_lds(16B) from pre-swizzled
// xpad.  A-fragments prefetched 2 taps ahead in a 3-slot register rotation.
__global__ __launch_bounds__(256, 2) void conv_mfma(
        const char* __restrict__ xpad,
        const __hip_bfloat16* __restrict__ wws,
        float* __restrict__ out) {
    __shared__ char xs[2][22528];

    int bid = blockIdx.x;
    int xcd = bid & 7, k = bid >> 3;               // 56 blocks per XCD
    int b   = xcd * 4 + k / 14;
    int rb  = k % 14;
    int row0 = rb * 4;
    int tid = threadIdx.x, wave = tid >> 6, lane = tid & 63;
    int cb = wave >> 1, wn = wave & 1;
    int cout0 = cb * 64;
    int l15 = lane & 15, lk = lane >> 4;

    const char* src = xpad + (size_t)b * 4 * PGB + (size_t)row0 * ROWB;

    // B-read bases per Ntile: bA (quarter shift s), bB (s+1), bC = dc==1 select
    int bA[7], bB[7], bC[7];
    #pragma unroll
    for (int i = 0; i < 7; i++) {
        int p = wn * 112 + i * 16 + l15;
        int r = p / 56, m = p % 56;
        int base = r * (int)ROWB + m * 64;
        bA[i] = base + ((lk + (m >> 1)) & 3) * 16;
        bB[i] = base + ((lk + (m >> 1) + 1) & 3) * 16;
        bC[i] = (m & 1) ? bB[i] : bA[i];
    }

    const __hip_bfloat16* ap = wws + (size_t)b * 9 * TAPSTR
                             + (size_t)(cout0 + l15) * CIN + lk * 8;

    f32x4 acc[4][7];
    #pragma unroll
    for (int mt = 0; mt < 4; mt++)
        #pragma unroll
        for (int i = 0; i < 7; i++) acc[mt][i] = (f32x4){0.f, 0.f, 0.f, 0.f};

    // A prologue: taps 0,1 of chunk 0
    bf16x8 areg[3][4];
    #pragma unroll
    for (int mt = 0; mt < 4; mt++)
        areg[0][mt] = *(const bf16x8*)(ap + (size_t)0 * TAPSTR + mt * 16 * CIN);
    #pragma unroll
    for (int mt = 0; mt < 4; mt++)
        areg[1][mt] = *(const bf16x8*)(ap + (size_t)1 * TAPSTR + mt * 16 * CIN);

    // staging prologue: chunk 0 (22 x 1KB loads split over 4 waves)
    #pragma unroll
    for (int i = 0; i < 6; i++) {
        int idx = i * 4 + wave;
        if (idx < 22) gload_lds16(src + idx * 1024 + lane * 16, &xs[0][idx * 1024]);
    }

    for (int g = 0; g < 4; ++g) {
        __syncthreads();                           // drains vmcnt -> xs[g&1] ready
        if (g < 3) {                               // issue next chunk; flies under MFMA
            const char* s2 = src + (size_t)(g + 1) * PGB;
            #pragma unroll
            for (int i = 0; i < 6; i++) {
                int idx = i * 4 + wave;
                if (idx < 22) gload_lds16(s2 + idx * 1024 + lane * 16, &xs[(g + 1) & 1][idx * 1024]);
            }
        }
        const char* xb = xs[g & 1];
        #pragma unroll
        for (int t = 0; t < 9; t++) {
            // prefetch A for flat tap (g*9 + t + 2) into slot (t+2)%3
            {
                const int tt = (t < 7) ? t + 2 : t - 7;
                const int gg_add = (t < 7) ? 0 : 1;
                int gg = g + gg_add;
                if (gg < 4) {
                    const __hip_bfloat16* pa = ap + (size_t)tt * TAPSTR + gg * 32;
                    #pragma unroll
                    for (int mt = 0; mt < 4; mt++)
                        areg[(t + 2) % 3][mt] = *(const bf16x8*)(pa + mt * 16 * CIN);
                }
            }
            const int dr = t / 3, dc = t % 3;
            const int imm = dr * (int)ROWB + dc * 64;
            #pragma unroll
            for (int i = 0; i < 7; i++) {
                int boff = (dc == 0) ? bA[i] : (dc == 1) ? bC[i] : bB[i];
                bf16x8 bv = *(const bf16x8*)(xb + boff + imm);
                #pragma unroll
                for (int mt = 0; mt < 4; mt++)
                    acc[mt][i] = __builtin_amdgcn_mfma_f32_16x16x32_bf16(
                        areg[t % 3][mt], bv, acc[mt][i], 0, 0, 0);
            }
        }
    }

    // epilogue: C/D layout col=lane&15 (pixel), row=(lane>>4)*4+j (cout)
    float* outb = out + (size_t)b * COUT * HW + row0 * 56;
    #pragma unroll
    for (int mt = 0; mt < 4; mt++) {
        int cbase = cout0 + mt * 16 + lk * 4;
        #pragma unroll
        for (int i = 0; i < 7; i++) {
            int pp = wn * 112 + i * 16 + l15;
            #pragma unroll
            for (int j = 0; j < 4; j++)
                outb[(size_t)(cbase + j) * HW + pp] = acc[mt][i][j];
        }
    }
}

// ---------------- launch ----------------
extern "C" void kernel_launch(void* const* d_in, const int* in_sizes, int n_in,
                              void* d_out, int out_size, void* d_ws, size_t ws_size,
                              hipStream_t stream) {
    const float* x  = (const float*)d_in[0];
    const float* cw = (const float*)d_in[1];
    const float* gw = (const float*)d_in[2];
    const float* gb = (const float*)d_in[3];

    float* out = (float*)d_out;
    char* ws = (char*)d_ws;
    char* xpad           = ws + XP_OFF;
    __hip_bfloat16* wws  = (__hip_bfloat16*)(ws + WW_OFF);
    float* hsum          = (float*)(ws + HS_OFF);
    float* gap           = (float*)(ws + GAP_OFF);
    GateInfo* info       = (GateInfo*)(ws + GI_OFF);
    float* wout = out + (size_t)Bn * COUT * HW;

    convert_kernel<<<Bn * Hh, 256, 0, stream>>>(x, xpad, hsum);
    gap2_kernel   <<<16,      256, 0, stream>>>(hsum, gap);
    gate_kernel   <<<1,       256, 0, stream>>>(gap, gw, gb, wout, info);
    wcomb_kernel  <<<Bn * 8,  256, 0, stream>>>(cw, info, wws);
    conv_mfma     <<<448,     256, 0, stream>>>(xpad, wws, out);
}

// Round 7
// 168.373 us; speedup vs baseline: 1.1202x; 1.0139x over previous
//
#include <hip/hip_runtime.h>
#include <hip/hip_bf16.h>

constexpr int Bn   = 32;
constexpr int CIN  = 128;
constexpr int Hh   = 56;
constexpr int Ww   = 56;
constexpr int HW   = Hh * Ww;      // 3136
constexpr int COUT = 128;
constexpr int En   = 8;

typedef __attribute__((ext_vector_type(8))) short bf16x8;   // 8 bf16 (4 VGPRs)
typedef __attribute__((ext_vector_type(4))) float f32x4;

struct GateInfo { int e0, e1; float w0, w1; };

// ---- xpad: [b][g=cin/32][row 0..57][col 0..57][4 quarters x 8 cin] bf16 ----
// quarter swizzle: physical quarter pq holds logical quarter (pq - (col>>1)) & 3
constexpr size_t ROWB = 58 * 64;            // 3712 B per padded row line
constexpr size_t PGB  = 58 * ROWB;          // 215,296 B per (b,g) plane
constexpr int TAPSTR  = COUT * CIN;         // 16384 elems per tap in wws

// ---- workspace layout (bytes) ----
constexpr size_t XP_OFF  = 0;
constexpr size_t XP_SZ   = (size_t)Bn * 4 * PGB;            // 27,557,888
constexpr size_t WW_OFF  = XP_OFF + XP_SZ;                  // bf16 combined W [b][tap][cout][cin]
constexpr size_t WW_SZ   = (size_t)Bn * 9 * COUT * CIN * 2; // 9,437,184
constexpr size_t HS_OFF  = WW_OFF + WW_SZ;                  // f32 per-(b,h,c) row sums
constexpr size_t HS_SZ   = (size_t)Bn * Hh * CIN * 4;
constexpr size_t GAP_OFF = HS_OFF + HS_SZ;
constexpr size_t GAP_SZ  = (size_t)Bn * CIN * 4;
constexpr size_t GI_OFF  = GAP_OFF + GAP_SZ;

__device__ inline void gload_lds16(const void* g, void* l) {
    __builtin_amdgcn_global_load_lds(
        (const __attribute__((address_space(1))) unsigned int*)g,
        (__attribute__((address_space(3))) unsigned int*)l, 16, 0, 0);
}

// ---------------- 1: NCHW f32 -> xpad bf16 (swizzled quarters), borders zeroed, row sums ----------------
// grid = Bn*Hh blocks (b,h), 256 threads
__global__ __launch_bounds__(256) void convert_kernel(const float* __restrict__ x,
        char* __restrict__ xpad, float* __restrict__ hsum) {
    __shared__ float lt[CIN * 57];   // [c][w], stride 57 (odd) for transpose reads
    int gid = blockIdx.x;
    int b = gid / Hh, h = gid % Hh;
    const float* xp = x + (size_t)b * CIN * HW + h * Ww;
    for (int u = threadIdx.x; u < CIN * Ww; u += 256) {
        int c = u / Ww, w = u % Ww;
        lt[c * 57 + w] = xp[(size_t)c * HW + w];
    }
    __syncthreads();
    char* dst = xpad + (size_t)b * 4 * PGB + (size_t)(h + 1) * ROWB;
    // 896 16B units: u = g*224 + w*4 + a; physical slot = (a + ((w+1)>>1)) & 3
    for (int u = threadIdx.x; u < 896; u += 256) {
        int g = u / 224, r = u % 224, w = r >> 2, a = r & 3;
        bf16x8 pk;
        #pragma unroll
        for (int j = 0; j < 8; j++) {
            __hip_bfloat16 t = __float2bfloat16(lt[(g * 32 + a * 8 + j) * 57 + w]);
            pk[j] = *reinterpret_cast<short*>(&t);
        }
        int pq = (a + ((w + 1) >> 1)) & 3;
        *(bf16x8*)(dst + (size_t)g * PGB + (size_t)(w + 1) * 64 + pq * 16) = pk;
    }
    // zero col borders (cols 0 and 57) for this row, all 4 g-planes
    if (threadIdx.x < 32) {
        int t = threadIdx.x, g = t >> 3, side = (t >> 2) & 1, q = t & 3;
        *(int4*)(xpad + (size_t)b * 4 * PGB + (size_t)g * PGB + (size_t)(h + 1) * ROWB
                 + (side ? 57 : 0) * 64 + q * 16) = (int4){0, 0, 0, 0};
    }
    // first/last h-blocks zero full rows 0 / 57
    if (h == 0 || h == 55) {
        int row = (h == 0) ? 0 : 57;
        char* base = xpad + (size_t)b * 4 * PGB + (size_t)row * ROWB;
        for (int u = threadIdx.x; u < 928; u += 256) {
            int g = u / 232, r = u % 232;
            *(int4*)(base + (size_t)g * PGB + (size_t)r * 16) = (int4){0, 0, 0, 0};
        }
    }
    if (threadIdx.x < CIN) {
        int c = threadIdx.x;
        float s = 0.f;
        #pragma unroll 8
        for (int w = 0; w < Ww; w++) s += lt[c * 57 + w];
        hsum[((size_t)b * Hh + h) * CIN + c] = s;
    }
}

// ---------------- 2: fused GAP finish + gate (logits -> top2 -> softmax) ----------------
// grid = Bn blocks (one per sample), 128 threads
__global__ __launch_bounds__(128) void gapgate_kernel(const float* __restrict__ hsum,
        const float* __restrict__ gate_w, const float* __restrict__ gate_b,
        float* __restrict__ wout, GateInfo* __restrict__ info) {
    __shared__ float gaps[CIN];
    __shared__ float lg[En];
    __shared__ GateInfo gsh;
    int b = blockIdx.x, tid = threadIdx.x;
    float s = 0.f;
    for (int h = 0; h < Hh; h++) s += hsum[((size_t)b * Hh + h) * CIN + tid];
    gaps[tid] = s * (1.f / (float)HW);
    __syncthreads();
    if (tid < En) {
        float t = gate_b[tid];
        #pragma unroll 8
        for (int c = 0; c < CIN; c++) t += gaps[c] * gate_w[tid * CIN + c];
        lg[tid] = t;
    }
    __syncthreads();
    if (tid == 0) {
        float v[En];
        #pragma unroll
        for (int k = 0; k < En; k++) v[k] = lg[k];
        int i0 = 0; float m0 = v[0];
        #pragma unroll
        for (int k = 1; k < En; k++) if (v[k] > m0) { m0 = v[k]; i0 = k; }
        int i1 = -1; float m1 = -1e30f;
        #pragma unroll
        for (int k = 0; k < En; k++) if (k != i0 && v[k] > m1) { m1 = v[k]; i1 = k; }
        float ex = expf(m1 - m0);
        float den = 1.f + ex;
        GateInfo t; t.e0 = i0; t.e1 = i1; t.w0 = 1.f / den; t.w1 = ex / den;
        gsh = t; info[b] = t;
    }
    __syncthreads();
    if (tid < En) {
        GateInfo t = gsh;
        wout[b * En + tid] = (tid == t.e0) ? t.w0 : (tid == t.e1) ? t.w1 : 0.f;
    }
}

// ---------------- 3: combined weights -> bf16 [b][tap][cout][cin] ----------------
// grid = Bn*8 blocks (b, cout-group of 16), 256 threads
__global__ __launch_bounds__(256) void wcomb_kernel(const float* __restrict__ cw,
        const GateInfo* __restrict__ info, __hip_bfloat16* __restrict__ wws) {
    __shared__ __hip_bfloat16 wl[16 * 1152];       // [co][cin][tap]
    int b = blockIdx.x >> 3, cg = blockIdx.x & 7;
    GateInfo gi = info[b];
    const float* p0 = cw + (size_t)gi.e0 * COUT * CIN * 9 + (size_t)cg * 16 * 1152;
    const float* p1 = cw + (size_t)gi.e1 * COUT * CIN * 9 + (size_t)cg * 16 * 1152;
    for (int u = threadIdx.x; u < 16 * 1152; u += 256)
        wl[u] = __float2bfloat16(gi.w0 * p0[u] + gi.w1 * p1[u]);
    __syncthreads();
    __hip_bfloat16* wo = wws + (size_t)b * 9 * COUT * CIN + (size_t)cg * 16 * CIN;
    // vectorized scatter: u = t*256 + co*16 + a  -> 16B store of 8 cins
    for (int u = threadIdx.x; u < 2304; u += 256) {
        int t = u >> 8, rem = u & 255, co = rem >> 4, a = rem & 15;
        bf16x8 pk;
        #pragma unroll
        for (int j = 0; j < 8; j++)
            pk[j] = *reinterpret_cast<short*>(&wl[co * 1152 + (a * 8 + j) * 9 + t]);
        *(bf16x8*)(wo + (size_t)t * COUT * CIN + co * CIN + a * 8) = pk;
    }
}

// ---------------- 4: implicit-GEMM conv via MFMA ----------------
// 224 blocks = 8 XCD x (4 samples x 7 row-blocks of 8) -> exactly <=1 block/CU,
// 512 thr = 8 waves (2 cout-halves x 4 pixel-quarters) = the 8-wave/CU register
// cap, perfectly balanced.  Wave tile: M=64 (Mrep=4) x N=112 (7 Ntiles).
// LDS: double-buffered 37120B slab = 10 padded rows x 58 cols x 64B, quarter-
// swizzled, staged linearly by global_load_lds(16B); next chunk issued before
// current chunk's compute.  A-fragments prefetched 2 taps ahead (3-slot ring).
__global__ __launch_bounds__(512, 2) void conv_mfma(
        const char* __restrict__ xpad,
        const __hip_bfloat16* __restrict__ wws,
        float* __restrict__ out) {
    __shared__ char xs[2][37120];

    int bid = blockIdx.x;
    int xcd = bid & 7, k = bid >> 3;               // 28 blocks per XCD
    int b   = xcd * 4 + k / 7;
    int rb  = k % 7;
    int row0 = rb * 8;
    int tid = threadIdx.x, wave = tid >> 6, lane = tid & 63;
    int cb = wave >> 2, wq = wave & 3;
    int cout0 = cb * 64;
    int l15 = lane & 15, lk = lane >> 4;

    const char* src = xpad + (size_t)b * 4 * PGB + (size_t)row0 * ROWB;

    // B-read bases per Ntile: bA (quarter shift s), bB (s+1), bC = dc==1 select
    int bA[7], bB[7], bC[7];
    #pragma unroll
    for (int i = 0; i < 7; i++) {
        int p = wq * 112 + i * 16 + l15;           // pixel within the 448-span
        int r = p / 56, m = p % 56;
        int base = r * (int)ROWB + m * 64;
        bA[i] = base + ((lk + (m >> 1)) & 3) * 16;
        bB[i] = base + ((lk + (m >> 1) + 1) & 3) * 16;
        bC[i] = (m & 1) ? bB[i] : bA[i];
    }

    const __hip_bfloat16* ap = wws + (size_t)b * 9 * TAPSTR
                             + (size_t)(cout0 + l15) * CIN + lk * 8;

    f32x4 acc[4][7];
    #pragma unroll
    for (int mt = 0; mt < 4; mt++)
        #pragma unroll
        for (int i = 0; i < 7; i++) acc[mt][i] = (f32x4){0.f, 0.f, 0.f, 0.f};

    // A prologue: taps 0,1 of chunk 0
    bf16x8 areg[3][4];
    #pragma unroll
    for (int mt = 0; mt < 4; mt++)
        areg[0][mt] = *(const bf16x8*)(ap + (size_t)0 * TAPSTR + mt * 16 * CIN);
    #pragma unroll
    for (int mt = 0; mt < 4; mt++)
        areg[1][mt] = *(const bf16x8*)(ap + (size_t)1 * TAPSTR + mt * 16 * CIN);

    // staging prologue: chunk 0 = 2320 16B units, 512 lanes sequential
    #pragma unroll
    for (int kk = 0; kk < 5; kk++) {
        int idx = kk * 512 + tid;
        if (idx < 2320) gload_lds16(src + (size_t)idx * 16, &xs[0][idx * 16]);
    }

    for (int g = 0; g < 4; ++g) {
        __syncthreads();                           // drains vmcnt -> xs[g&1] ready
        if (g < 3) {                               // issue next chunk; flies under MFMA
            const char* s2 = src + (size_t)(g + 1) * PGB;
            #pragma unroll
            for (int kk = 0; kk < 5; kk++) {
                int idx = kk * 512 + tid;
                if (idx < 2320) gload_lds16(s2 + (size_t)idx * 16, &xs[(g + 1) & 1][idx * 16]);
            }
        }
        const char* xb = xs[g & 1];
        #pragma unroll
        for (int t = 0; t < 9; t++) {
            // prefetch A for flat tap (g*9 + t + 2) into slot (t+2)%3
            {
                const int tt = (t < 7) ? t + 2 : t - 7;
                const int gg_add = (t < 7) ? 0 : 1;
                int gg = g + gg_add;
                if (gg < 4) {
                    const __hip_bfloat16* pa = ap + (size_t)tt * TAPSTR + gg * 32;
                    #pragma unroll
                    for (int mt = 0; mt < 4; mt++)
                        areg[(t + 2) % 3][mt] = *(const bf16x8*)(pa + mt * 16 * CIN);
                }
            }
            const int dr = t / 3, dc = t % 3;
            const int imm = dr * (int)ROWB + dc * 64;
            #pragma unroll
            for (int i = 0; i < 7; i++) {
                int boff = (dc == 0) ? bA[i] : (dc == 1) ? bC[i] : bB[i];
                bf16x8 bv = *(const bf16x8*)(xb + boff + imm);
                #pragma unroll
                for (int mt = 0; mt < 4; mt++)
                    acc[mt][i] = __builtin_amdgcn_mfma_f32_16x16x32_bf16(
                        areg[t % 3][mt], bv, acc[mt][i], 0, 0, 0);
            }
        }
    }

    // epilogue: C/D layout col=lane&15 (pixel), row=(lane>>4)*4+j (cout)
    float* outb = out + (size_t)b * COUT * HW + row0 * 56;
    #pragma unroll
    for (int mt = 0; mt < 4; mt++) {
        int cbase = cout0 + mt * 16 + lk * 4;
        #pragma unroll
        for (int i = 0; i < 7; i++) {
            int pp = wq * 112 + i * 16 + l15;
            #pragma unroll
            for (int j = 0; j < 4; j++)
                outb[(size_t)(cbase + j) * HW + pp] = acc[mt][i][j];
        }
    }
}

// ---------------- launch ----------------
extern "C" void kernel_launch(void* const* d_in, const int* in_sizes, int n_in,
                              void* d_out, int out_size, void* d_ws, size_t ws_size,
                              hipStream_t stream) {
    const float* x  = (const float*)d_in[0];
    const float* cw = (const float*)d_in[1];
    const float* gw = (const float*)d_in[2];
    const float* gb = (const float*)d_in[3];

    float* out = (float*)d_out;
    char* ws = (char*)d_ws;
    char* xpad           = ws + XP_OFF;
    __hip_bfloat16* wws  = (__hip_bfloat16*)(ws + WW_OFF);
    float* hsum          = (float*)(ws + HS_OFF);
    GateInfo* info       = (GateInfo*)(ws + GI_OFF);
    float* wout = out + (size_t)Bn * COUT * HW;

    convert_kernel<<<Bn * Hh, 256, 0, stream>>>(x, xpad, hsum);
    gapgate_kernel<<<Bn,      128, 0, stream>>>(hsum, gw, gb, wout, info);
    wcomb_kernel  <<<Bn * 8,  256, 0, stream>>>(cw, info, wws);
    conv_mfma     <<<224,     512, 0, stream>>>(xpad, wws, out);
}